// Round 1
// 1229.329 us; speedup vs baseline: 1.1546x; 1.1546x over previous
//
#include <hip/hip_runtime.h>

// Sizes (fixed by the problem)
#define NB  128
#define ND  1024
#define NH1 512
#define NH2 128

typedef __attribute__((ext_vector_type(8))) short short8;   // 8 x bf16 (4 VGPRs)
typedef __attribute__((ext_vector_type(4))) float f32x4;    // MFMA accumulator

__device__ __forceinline__ float sigm(float v) { return 1.0f / (1.0f + __expf(-v)); }

// Split fp32 into bf16 hi + bf16 lo (truncation; lo compensates hi's error).
// v ≈ hi + lo with |v - hi - lo| <= 2^-16 |v|.
__device__ __forceinline__ void bsplit(float v, unsigned short& h, unsigned short& l) {
    unsigned hu = __float_as_uint(v) & 0xffff0000u;
    h = (unsigned short)(hu >> 16);
    float r = v - __uint_as_float(hu);
    l = (unsigned short)(__float_as_uint(r) >> 16);
}

// ---------------------------------------------------------------------------
// Forward FC (unchanged, known-good): out[r,c] = act(dot(X[r,:K], W[c,:K]) + b[c])
// ---------------------------------------------------------------------------
template<int K, int COLS, bool SIG>
__global__ __launch_bounds__(256)
void fc_kernel(const float* __restrict__ X, const float* __restrict__ W,
               const float* __restrict__ bias, float* __restrict__ Cout,
               float* __restrict__ Sout) {
    int idx = blockIdx.x * 256 + threadIdx.x;
    int r = idx / COLS, c = idx % COLS;
    const float4* xr = (const float4*)(X + (long)r * K);
    const float4* wr = (const float4*)(W + (long)c * K);
    float acc = 0.f;
#pragma unroll 4
    for (int k = 0; k < K / 4; k++) {
        float4 a = xr[k], b = wr[k];
        acc += a.x * b.x + a.y * b.y + a.z * b.z + a.w * b.w;
    }
    acc += bias[c];
    if (SIG) {
        float cv = sigm(acc);
        Cout[idx] = cv;
        Sout[idx] = cv * (1.f - cv);
    } else {
        Cout[idx] = acc;
    }
}

// ---------------------------------------------------------------------------
// fp32 GEMM, 128x128 tile, 256 threads, 8x8 per thread, BK=8.
// C = (A .* ks[b][k]) @ B  (A [M,K], B [K,N] row-major, both batch-shared),
// optionally col-scaled by ns[b][n]. Epilogue writes bf16 hi/lo split:
//   TRANS=false: Oh/Ol[b][m][n]   (k-major consumer layout for L)
//   TRANS=true : Oh/Ol[b][n][m]   (transposed, k-major consumer layout for R)
// ---------------------------------------------------------------------------
template<int K, bool KSCALE, bool NSCALE, bool TRANS>
__global__ __launch_bounds__(256)
void gemm128_split(const float* __restrict__ A, const float* __restrict__ Bm,
                   const float* __restrict__ ks, const float* __restrict__ ns,
                   unsigned short* __restrict__ Oh, unsigned short* __restrict__ Ol,
                   long oBs, int M, int N) {
    int b = blockIdx.z;
    int m0 = blockIdx.y * 128, n0 = blockIdx.x * 128;
    __shared__ float As[8][128];   // k-major A tile
    __shared__ float Bs[8][128];
    int t  = threadIdx.x;
    int tx = t & 15, ty = t >> 4;        // thread owns m in {ty*4..+4, +64}, n in {tx*4..+4, +64}
    int lar = t >> 1, lak = (t & 1) * 4; // A load: row, k-offset (128 rows x 8 k = 256 float4)
    int lbk = t >> 5, lbn = (t & 31) * 4;// B load: k-row, n-offset (8 rows x 128 n)

    float acc[8][8] = {{0.f}};

    for (int k0 = 0; k0 < K; k0 += 8) {
        float4 av = *(const float4*)(A + (long)(m0 + lar) * K + k0 + lak);
        if (KSCALE) {
            float4 sv = *(const float4*)(ks + (long)b * K + k0 + lak);
            av.x *= sv.x; av.y *= sv.y; av.z *= sv.z; av.w *= sv.w;
        }
        float4 bv = *(const float4*)(Bm + (long)(k0 + lbk) * N + n0 + lbn);
        __syncthreads();   // previous tile's compute done before overwrite
        As[lak + 0][lar] = av.x; As[lak + 1][lar] = av.y;
        As[lak + 2][lar] = av.z; As[lak + 3][lar] = av.w;
        *(float4*)(&Bs[lbk][lbn]) = bv;
        __syncthreads();
#pragma unroll
        for (int kk = 0; kk < 8; kk++) {
            float4 a0 = *(const float4*)(&As[kk][ty * 4]);
            float4 a1 = *(const float4*)(&As[kk][ty * 4 + 64]);
            float4 b0 = *(const float4*)(&Bs[kk][tx * 4]);
            float4 b1 = *(const float4*)(&Bs[kk][tx * 4 + 64]);
            float am[8] = {a0.x, a0.y, a0.z, a0.w, a1.x, a1.y, a1.z, a1.w};
            float bn[8] = {b0.x, b0.y, b0.z, b0.w, b1.x, b1.y, b1.z, b1.w};
#pragma unroll
            for (int i = 0; i < 8; i++)
#pragma unroll
                for (int j = 0; j < 8; j++) acc[i][j] += am[i] * bn[j];
        }
    }

    float nsc[8] = {1.f, 1.f, 1.f, 1.f, 1.f, 1.f, 1.f, 1.f};
    if (NSCALE) {
        float4 v0 = *(const float4*)(ns + (long)b * N + n0 + tx * 4);
        float4 v1 = *(const float4*)(ns + (long)b * N + n0 + tx * 4 + 64);
        nsc[0] = v0.x; nsc[1] = v0.y; nsc[2] = v0.z; nsc[3] = v0.w;
        nsc[4] = v1.x; nsc[5] = v1.y; nsc[6] = v1.z; nsc[7] = v1.w;
    }
    unsigned short* OhB = Oh + (long)b * oBs;
    unsigned short* OlB = Ol + (long)b * oBs;

    if (!TRANS) {
#pragma unroll
        for (int i = 0; i < 8; i++) {
            int m = m0 + ty * 4 + (i & 3) + ((i >> 2) << 6);
#pragma unroll
            for (int jh = 0; jh < 2; jh++) {
                unsigned short hq[4], lq[4];
#pragma unroll
                for (int r = 0; r < 4; r++) {
                    float v = acc[i][jh * 4 + r];
                    if (NSCALE) v *= nsc[jh * 4 + r];
                    bsplit(v, hq[r], lq[r]);
                }
                long off = (long)m * N + n0 + tx * 4 + jh * 64;
                *(ushort4*)(OhB + off) = make_ushort4(hq[0], hq[1], hq[2], hq[3]);
                *(ushort4*)(OlB + off) = make_ushort4(lq[0], lq[1], lq[2], lq[3]);
            }
        }
    } else {
#pragma unroll
        for (int j = 0; j < 8; j++) {
            int n = n0 + tx * 4 + (j & 3) + ((j >> 2) << 6);
#pragma unroll
            for (int ih = 0; ih < 2; ih++) {
                unsigned short hq[4], lq[4];
#pragma unroll
                for (int r = 0; r < 4; r++) {
                    float v = acc[ih * 4 + r][j];
                    if (NSCALE) v *= nsc[j];
                    bsplit(v, hq[r], lq[r]);
                }
                long off = (long)n * M + m0 + ty * 4 + ih * 64;
                *(ushort4*)(OhB + off) = make_ushort4(hq[0], hq[1], hq[2], hq[3]);
                *(ushort4*)(OlB + off) = make_ushort4(lq[0], lq[1], lq[2], lq[3]);
            }
        }
    }
}

// ---------------------------------------------------------------------------
// Jac[b] = L[b] @ R[b] via bf16x3 MFMA (hi*hi + hi*lo + lo*hi).
// L stored [m][k] (k-contiguous), R stored transposed [n][k] (k-contiguous),
// so every MFMA fragment is one 16B load. M=N=1024, K=128.
// Block: 256 thr = 4 waves (2x2), 128x128 tile; wave = 64x64 = 4x4 MFMA tiles.
// mfma_f32_16x16x32_bf16 layouts (m89-verified):
//   A: lane holds A[l&15][8*(l>>4)+j]; B: lane holds B[8*(l>>4)+j][l&15];
//   D: col = l&15, row = 4*(l>>4)+reg.
// ---------------------------------------------------------------------------
__global__ __launch_bounds__(256)
void jac_mfma(const unsigned short* __restrict__ Lh, const unsigned short* __restrict__ Ll,
              const unsigned short* __restrict__ Rh, const unsigned short* __restrict__ Rl,
              float* __restrict__ J) {
    int b = blockIdx.z;
    long base = (long)b * ((long)ND * NH2);
    const unsigned short* Lhb = Lh + base;
    const unsigned short* Llb = Ll + base;
    const unsigned short* Rhb = Rh + base;
    const unsigned short* Rlb = Rl + base;

    int t = threadIdx.x;
    int lane = t & 63, w = t >> 6;
    int wr = w >> 1, wc = w & 1;
    int m0 = blockIdx.y * 128 + wr * 64;
    int n0 = blockIdx.x * 128 + wc * 64;
    int lrow = lane & 15;
    int lk   = (lane >> 4) << 3;   // k-offset within 32-chunk

    f32x4 zero = {0.f, 0.f, 0.f, 0.f};
    f32x4 acc[4][4];
#pragma unroll
    for (int i = 0; i < 4; i++)
#pragma unroll
        for (int j = 0; j < 4; j++) acc[i][j] = zero;

#pragma unroll
    for (int kc = 0; kc < NH2; kc += 32) {
        short8 ah[4], al[4], bh[4], bl[4];
#pragma unroll
        for (int i = 0; i < 4; i++) {
            long ao = (long)(m0 + i * 16 + lrow) * NH2 + kc + lk;
            ah[i] = *(const short8*)(Lhb + ao);
            al[i] = *(const short8*)(Llb + ao);
            long bo = (long)(n0 + i * 16 + lrow) * NH2 + kc + lk;
            bh[i] = *(const short8*)(Rhb + bo);
            bl[i] = *(const short8*)(Rlb + bo);
        }
#pragma unroll
        for (int i = 0; i < 4; i++)
#pragma unroll
            for (int j = 0; j < 4; j++) {
                acc[i][j] = __builtin_amdgcn_mfma_f32_16x16x32_bf16(ah[i], bh[j], acc[i][j], 0, 0, 0);
                acc[i][j] = __builtin_amdgcn_mfma_f32_16x16x32_bf16(ah[i], bl[j], acc[i][j], 0, 0, 0);
                acc[i][j] = __builtin_amdgcn_mfma_f32_16x16x32_bf16(al[i], bh[j], acc[i][j], 0, 0, 0);
            }
    }

    float* Jb = J + (long)b * ND * ND;
    int rbase = (lane >> 4) << 2;
    int ccol  = lane & 15;
#pragma unroll
    for (int i = 0; i < 4; i++)
#pragma unroll
        for (int r = 0; r < 4; r++) {
            long row = m0 + i * 16 + rbase + r;
            float* dst = Jb + row * ND + n0 + ccol;
#pragma unroll
            for (int j = 0; j < 4; j++) dst[j * 16] = acc[i][j][r];
        }
}

extern "C" void kernel_launch(void* const* d_in, const int* in_sizes, int n_in,
                              void* d_out, int out_size, void* d_ws, size_t ws_size,
                              hipStream_t stream) {
    const float* x  = (const float*)d_in[0];
    const float* W1 = (const float*)d_in[1];
    const float* b1 = (const float*)d_in[2];
    const float* W2 = (const float*)d_in[3];
    const float* b2 = (const float*)d_in[4];
    const float* W3 = (const float*)d_in[5];
    const float* b3 = (const float*)d_in[6];
    const float* W4 = (const float*)d_in[7];
    const float* b4 = (const float*)d_in[8];

    // Output layout: recover [128*1024] | c2 [128*128] | Jac [128*1024*1024]
    float* out_rec = (float*)d_out;
    float* out_c2  = out_rec + NB * ND;
    float* out_jac = out_c2 + NB * NH2;

    // Workspace: c1,s1,s2,c3,s3 fp32 | Lh,Ll,Rh,Rl bf16 [B,1024,128] each
    float* ws = (float*)d_ws;
    float* c1 = ws;                       // 65536
    float* s1 = c1 + NB * NH1;            // 65536
    float* s2 = s1 + NB * NH1;            // 16384
    float* c3 = s2 + NB * NH2;            // 65536
    float* s3 = c3 + NB * NH1;            // 65536
    unsigned short* Lh = (unsigned short*)(s3 + NB * NH1);
    unsigned short* Ll = Lh + (long)NB * ND * NH2;   // 16.78M ushort each
    unsigned short* Rh = Ll + (long)NB * ND * NH2;
    unsigned short* Rl = Rh + (long)NB * ND * NH2;

    // Forward pass (stores c & s = c*(1-c))
    fc_kernel<ND,  NH1, true ><<<NB * NH1 / 256, 256, 0, stream>>>(x,       W1, b1, c1,      s1);
    fc_kernel<NH1, NH2, true ><<<NB * NH2 / 256, 256, 0, stream>>>(c1,      W2, b2, out_c2,  s2);
    fc_kernel<NH2, NH1, true ><<<NB * NH1 / 256, 256, 0, stream>>>(out_c2,  W3, b3, c3,      s3);
    fc_kernel<NH1, ND,  false><<<NB * ND  / 256, 256, 0, stream>>>(c3,      W4, b4, out_rec, nullptr);

    // R^T[b][n][k] = ((W2 .* s1[b]) @ W1)^T : M=128, N=1024, K=512, split+transposed
    gemm128_split<NH1, true, false, true><<<dim3(ND / 128, NH2 / 128, NB), 256, 0, stream>>>(
        W2, W1, s1, nullptr, Rh, Rl, (long)NH2 * ND, NH2, ND);

    // L[b][m][k] = ((W4 .* s3[b]) @ W3) .* s2[b] : M=1024, N=128, K=512, split
    gemm128_split<NH1, true, true, false><<<dim3(NH2 / 128, ND / 128, NB), 256, 0, stream>>>(
        W4, W3, s3, s2, Lh, Ll, (long)ND * NH2, ND, NH2);

    // Jac[b] = L[b] @ R[b] : M=N=1024, K=128, bf16x3 MFMA
    jac_mfma<<<dim3(ND / 128, ND / 128, NB), 256, 0, stream>>>(Lh, Ll, Rh, Rl, out_jac);
}

// Round 2
// 1129.736 us; speedup vs baseline: 1.2564x; 1.0882x over previous
//
#include <hip/hip_runtime.h>

// Sizes (fixed by the problem)
#define NB  128
#define ND  1024
#define NH1 512
#define NH2 128

typedef __attribute__((ext_vector_type(8))) short short8;   // 8 x bf16 (4 VGPRs)
typedef __attribute__((ext_vector_type(4))) float f32x4;    // MFMA accumulator

__device__ __forceinline__ float sigm(float v) { return 1.0f / (1.0f + __expf(-v)); }

// Split fp32 into bf16 hi + bf16 lo (truncation; lo compensates hi's error).
// v ≈ hi + lo with |v - hi - lo| <= 2^-16 |v|.
__device__ __forceinline__ void bsplit(float v, unsigned short& h, unsigned short& l) {
    unsigned hu = __float_as_uint(v) & 0xffff0000u;
    h = (unsigned short)(hu >> 16);
    float r = v - __uint_as_float(hu);
    l = (unsigned short)(__float_as_uint(r) >> 16);
}

// ---------------------------------------------------------------------------
// Forward FC (known-good): out[r,c] = act(dot(X[r,:K], W[c,:K]) + b[c])
// ---------------------------------------------------------------------------
template<int K, int COLS, bool SIG>
__global__ __launch_bounds__(256)
void fc_kernel(const float* __restrict__ X, const float* __restrict__ W,
               const float* __restrict__ bias, float* __restrict__ Cout,
               float* __restrict__ Sout) {
    int idx = blockIdx.x * 256 + threadIdx.x;
    int r = idx / COLS, c = idx % COLS;
    const float4* xr = (const float4*)(X + (long)r * K);
    const float4* wr = (const float4*)(W + (long)c * K);
    float acc = 0.f;
#pragma unroll 4
    for (int k = 0; k < K / 4; k++) {
        float4 a = xr[k], b = wr[k];
        acc += a.x * b.x + a.y * b.y + a.z * b.z + a.w * b.w;
    }
    acc += bias[c];
    if (SIG) {
        float cv = sigm(acc);
        Cout[idx] = cv;
        Sout[idx] = cv * (1.f - cv);
    } else {
        Cout[idx] = acc;
    }
}

// ---------------------------------------------------------------------------
// One-time weight splits (batch-shared MFMA A operands, k-contiguous):
//   W1t[d][j] = W1[j][d]  (so R^T = W1t @ Br^T uses k=j contiguous)
//   W4 [o][j]             (already k-contiguous)
// idx over [1024][512].
// ---------------------------------------------------------------------------
__global__ __launch_bounds__(256)
void prep_shared(const float* __restrict__ W1, const float* __restrict__ W4,
                 unsigned short* __restrict__ W1th, unsigned short* __restrict__ W1tl,
                 unsigned short* __restrict__ W4h,  unsigned short* __restrict__ W4l) {
    int idx = blockIdx.x * 256 + threadIdx.x;
    int d = idx >> 9, j = idx & 511;
    unsigned short h, l;
    bsplit(W1[(long)j * ND + d], h, l);   // W1 [512][1024], read col d
    W1th[idx] = h; W1tl[idx] = l;
    bsplit(W4[idx], h, l);                // W4 [1024][512], direct
    W4h[idx] = h; W4l[idx] = l;
}

// ---------------------------------------------------------------------------
// Per-batch MFMA B operands ([n][k] layout, k-contiguous), k-scale absorbed:
//   Br[b][i][j] = W2[i][j] * s1[b][j]      (B of R^T gemm; i is out-col)
//   Bl[b][i][j] = W3[j][i] * s3[b][j]      (B of L   gemm)
// idx over [NB][128][512].
// ---------------------------------------------------------------------------
__global__ __launch_bounds__(256)
void prep_batch(const float* __restrict__ W2, const float* __restrict__ W3,
                const float* __restrict__ s1, const float* __restrict__ s3,
                unsigned short* __restrict__ Brh, unsigned short* __restrict__ Brl,
                unsigned short* __restrict__ Blh, unsigned short* __restrict__ Bll) {
    long idx = (long)blockIdx.x * 256 + threadIdx.x;
    int j = idx & 511;
    int i = (idx >> 9) & 127;
    int b = idx >> 16;
    float s1v = s1[(long)b * NH1 + j];
    float s3v = s3[(long)b * NH1 + j];
    unsigned short h, l;
    bsplit(W2[(long)i * NH1 + j] * s1v, h, l);
    Brh[idx] = h; Brl[idx] = l;
    bsplit(W3[(long)j * NH2 + i] * s3v, h, l);
    Blh[idx] = h; Bll[idx] = l;
}

// ---------------------------------------------------------------------------
// bf16x3 MFMA GEMM, M=1024, N=128, K=512:
//   O[b][m][n] = (sum_k A[m][k] * B[b][n][k]) * (NSCALE ? ns[b][n] : 1)
// A batch-shared h/l [1024][512]; B per-batch h/l [128][512]; both k-contig,
// fragments loaded straight from global (L2-resident). Output written as
// bf16 hi/lo split [b][m][n] — exactly the jac_mfma input layout.
// Block: 256 thr = 4 waves (2x2), 128x128 tile; wave 64x64 = 4x4 MFMA tiles.
// ---------------------------------------------------------------------------
template<bool NSCALE>
__global__ __launch_bounds__(256)
void mfma_nk(const unsigned short* __restrict__ Ah, const unsigned short* __restrict__ Al,
             const unsigned short* __restrict__ Bh, const unsigned short* __restrict__ Bl,
             const float* __restrict__ ns,
             unsigned short* __restrict__ Oh, unsigned short* __restrict__ Ol) {
    int b = blockIdx.z;
    const unsigned short* Bhb = Bh + (long)b * NH2 * NH1;
    const unsigned short* Blb = Bl + (long)b * NH2 * NH1;

    int t = threadIdx.x;
    int lane = t & 63, w = t >> 6;
    int wr = w >> 1, wc = w & 1;
    int m0 = blockIdx.x * 128 + wr * 64;
    int n0 = wc * 64;
    int lrow = lane & 15;
    int lk   = (lane >> 4) << 3;

    f32x4 zero = {0.f, 0.f, 0.f, 0.f};
    f32x4 acc[4][4];
#pragma unroll
    for (int i = 0; i < 4; i++)
#pragma unroll
        for (int j = 0; j < 4; j++) acc[i][j] = zero;

#pragma unroll 2
    for (int kc = 0; kc < NH1; kc += 32) {
        short8 ah[4], al[4], bh[4], bl[4];
#pragma unroll
        for (int i = 0; i < 4; i++) {
            long ao = (long)(m0 + i * 16 + lrow) * NH1 + kc + lk;
            ah[i] = *(const short8*)(Ah + ao);
            al[i] = *(const short8*)(Al + ao);
            long bo = (long)(n0 + i * 16 + lrow) * NH1 + kc + lk;
            bh[i] = *(const short8*)(Bhb + bo);
            bl[i] = *(const short8*)(Blb + bo);
        }
#pragma unroll
        for (int i = 0; i < 4; i++)
#pragma unroll
            for (int j = 0; j < 4; j++) {
                acc[i][j] = __builtin_amdgcn_mfma_f32_16x16x32_bf16(ah[i], bh[j], acc[i][j], 0, 0, 0);
                acc[i][j] = __builtin_amdgcn_mfma_f32_16x16x32_bf16(ah[i], bl[j], acc[i][j], 0, 0, 0);
                acc[i][j] = __builtin_amdgcn_mfma_f32_16x16x32_bf16(al[i], bh[j], acc[i][j], 0, 0, 0);
            }
    }

    float nsc[4] = {1.f, 1.f, 1.f, 1.f};
    if (NSCALE) {
#pragma unroll
        for (int j = 0; j < 4; j++) nsc[j] = ns[(long)b * NH2 + n0 + j * 16 + lrow];
    }
    unsigned short* OhB = Oh + (long)b * ND * NH2;
    unsigned short* OlB = Ol + (long)b * ND * NH2;
    int rbase = (lane >> 4) << 2;
#pragma unroll
    for (int i = 0; i < 4; i++)
#pragma unroll
        for (int r = 0; r < 4; r++) {
            long row = m0 + i * 16 + rbase + r;
#pragma unroll
            for (int j = 0; j < 4; j++) {
                float v = acc[i][j][r] * nsc[j];
                unsigned short h, l;
                bsplit(v, h, l);
                long off = row * NH2 + n0 + j * 16 + lrow;
                OhB[off] = h;
                OlB[off] = l;
            }
        }
}

// ---------------------------------------------------------------------------
// Jac[b] = L[b] @ R[b] via bf16x3 MFMA (hi*hi + hi*lo + lo*hi).
// L stored [m][k] (k-contiguous), R stored transposed [n][k] (k-contiguous).
// M=N=1024, K=128. Block: 4 waves (2x2), 128x128 tile.
// mfma_f32_16x16x32_bf16: D col = lane&15, row = 4*(lane>>4)+reg (m89).
// ---------------------------------------------------------------------------
__global__ __launch_bounds__(256)
void jac_mfma(const unsigned short* __restrict__ Lh, const unsigned short* __restrict__ Ll,
              const unsigned short* __restrict__ Rh, const unsigned short* __restrict__ Rl,
              float* __restrict__ J) {
    int b = blockIdx.z;
    long base = (long)b * ((long)ND * NH2);
    const unsigned short* Lhb = Lh + base;
    const unsigned short* Llb = Ll + base;
    const unsigned short* Rhb = Rh + base;
    const unsigned short* Rlb = Rl + base;

    int t = threadIdx.x;
    int lane = t & 63, w = t >> 6;
    int wr = w >> 1, wc = w & 1;
    int m0 = blockIdx.y * 128 + wr * 64;
    int n0 = blockIdx.x * 128 + wc * 64;
    int lrow = lane & 15;
    int lk   = (lane >> 4) << 3;

    f32x4 zero = {0.f, 0.f, 0.f, 0.f};
    f32x4 acc[4][4];
#pragma unroll
    for (int i = 0; i < 4; i++)
#pragma unroll
        for (int j = 0; j < 4; j++) acc[i][j] = zero;

#pragma unroll
    for (int kc = 0; kc < NH2; kc += 32) {
        short8 ah[4], al[4], bh[4], bl[4];
#pragma unroll
        for (int i = 0; i < 4; i++) {
            long ao = (long)(m0 + i * 16 + lrow) * NH2 + kc + lk;
            ah[i] = *(const short8*)(Lhb + ao);
            al[i] = *(const short8*)(Llb + ao);
            long bo = (long)(n0 + i * 16 + lrow) * NH2 + kc + lk;
            bh[i] = *(const short8*)(Rhb + bo);
            bl[i] = *(const short8*)(Rlb + bo);
        }
#pragma unroll
        for (int i = 0; i < 4; i++)
#pragma unroll
            for (int j = 0; j < 4; j++) {
                acc[i][j] = __builtin_amdgcn_mfma_f32_16x16x32_bf16(ah[i], bh[j], acc[i][j], 0, 0, 0);
                acc[i][j] = __builtin_amdgcn_mfma_f32_16x16x32_bf16(ah[i], bl[j], acc[i][j], 0, 0, 0);
                acc[i][j] = __builtin_amdgcn_mfma_f32_16x16x32_bf16(al[i], bh[j], acc[i][j], 0, 0, 0);
            }
    }

    float* Jb = J + (long)b * ND * ND;
    int rbase = (lane >> 4) << 2;
    int ccol  = lane & 15;
#pragma unroll
    for (int i = 0; i < 4; i++)
#pragma unroll
        for (int r = 0; r < 4; r++) {
            long row = m0 + i * 16 + rbase + r;
            float* dst = Jb + row * ND + n0 + ccol;
#pragma unroll
            for (int j = 0; j < 4; j++) dst[j * 16] = acc[i][j][r];
        }
}

extern "C" void kernel_launch(void* const* d_in, const int* in_sizes, int n_in,
                              void* d_out, int out_size, void* d_ws, size_t ws_size,
                              hipStream_t stream) {
    const float* x  = (const float*)d_in[0];
    const float* W1 = (const float*)d_in[1];
    const float* b1 = (const float*)d_in[2];
    const float* W2 = (const float*)d_in[3];
    const float* b2 = (const float*)d_in[4];
    const float* W3 = (const float*)d_in[5];
    const float* b3 = (const float*)d_in[6];
    const float* W4 = (const float*)d_in[7];
    const float* b4 = (const float*)d_in[8];

    // Output layout: recover [128*1024] | c2 [128*128] | Jac [128*1024*1024]
    float* out_rec = (float*)d_out;
    float* out_c2  = out_rec + NB * ND;
    float* out_jac = out_c2 + NB * NH2;

    // Workspace: fp32 c1,s1,s2,c3,s3 | ushort splits
    float* ws = (float*)d_ws;
    float* c1 = ws;                       // 65536
    float* s1 = c1 + NB * NH1;            // 65536
    float* s2 = s1 + NB * NH1;            // 16384
    float* c3 = s2 + NB * NH2;            // 65536
    float* s3 = c3 + NB * NH1;            // 65536
    unsigned short* us = (unsigned short*)(s3 + NB * NH1);
    unsigned short* W1th = us;                          // 524288 each
    unsigned short* W1tl = W1th + (long)ND * NH1;
    unsigned short* W4h  = W1tl + (long)ND * NH1;
    unsigned short* W4l  = W4h  + (long)ND * NH1;
    unsigned short* Brh  = W4l  + (long)ND * NH1;       // 8388608 each
    unsigned short* Brl  = Brh  + (long)NB * NH2 * NH1;
    unsigned short* Blh  = Brl  + (long)NB * NH2 * NH1;
    unsigned short* Bll  = Blh  + (long)NB * NH2 * NH1;
    unsigned short* Lh   = Bll  + (long)NB * NH2 * NH1; // 16777216 each
    unsigned short* Ll   = Lh   + (long)NB * ND * NH2;
    unsigned short* Rh   = Ll   + (long)NB * ND * NH2;
    unsigned short* Rl   = Rh   + (long)NB * ND * NH2;

    // Forward pass (stores c & s = c*(1-c))
    fc_kernel<ND,  NH1, true ><<<NB * NH1 / 256, 256, 0, stream>>>(x,       W1, b1, c1,      s1);
    fc_kernel<NH1, NH2, true ><<<NB * NH2 / 256, 256, 0, stream>>>(c1,      W2, b2, out_c2,  s2);
    fc_kernel<NH2, NH1, true ><<<NB * NH1 / 256, 256, 0, stream>>>(out_c2,  W3, b3, c3,      s3);
    fc_kernel<NH1, ND,  false><<<NB * ND  / 256, 256, 0, stream>>>(c3,      W4, b4, out_rec, nullptr);

    // One-time bf16 splits of shared A operands (W1^T, W4)
    prep_shared<<<ND * NH1 / 256, 256, 0, stream>>>(W1, W4, W1th, W1tl, W4h, W4l);

    // Per-batch k-scaled B operands (W2.*s1, W3t.*s3)
    prep_batch<<<(long)NB * NH2 * NH1 / 256, 256, 0, stream>>>(
        W2, W3, s1, s3, Brh, Brl, Blh, Bll);

    // R^T[b][d][i] = sum_j W1t[d][j] * Br[b][i][j]   : M=1024, N=128, K=512
    mfma_nk<false><<<dim3(ND / 128, 1, NB), 256, 0, stream>>>(
        W1th, W1tl, Brh, Brl, nullptr, Rh, Rl);

    // L[b][o][i] = (sum_j W4[o][j] * Bl[b][i][j]) * s2[b][i] : M=1024, N=128, K=512
    mfma_nk<true><<<dim3(ND / 128, 1, NB), 256, 0, stream>>>(
        W4h, W4l, Blh, Bll, s2, Lh, Ll);

    // Jac[b] = L[b] @ R[b] : M=N=1024, K=128, bf16x3 MFMA
    jac_mfma<<<dim3(ND / 128, ND / 128, NB), 256, 0, stream>>>(Lh, Ll, Rh, Rl, out_jac);
}

// Round 3
// 1055.070 us; speedup vs baseline: 1.3453x; 1.0708x over previous
//
#include <hip/hip_runtime.h>

// Sizes (fixed by the problem)
#define NB  128
#define ND  1024
#define NH1 512
#define NH2 128

typedef __attribute__((ext_vector_type(8))) short short8;   // 8 x bf16 (4 VGPRs)
typedef __attribute__((ext_vector_type(4))) float f32x4;    // MFMA accumulator / vec store

__device__ __forceinline__ float sigm(float v) { return 1.0f / (1.0f + __expf(-v)); }

// Split fp32 into bf16 hi + bf16 lo (lo compensates hi's truncation error).
// v ≈ hi + lo with |v - hi - lo| <= ~2^-16 |v|.
__device__ __forceinline__ void bsplit(float v, unsigned short& h, unsigned short& l) {
    unsigned hu = __float_as_uint(v) & 0xffff0000u;
    h = (unsigned short)(hu >> 16);
    float r = v - __uint_as_float(hu);
    l = (unsigned short)(__float_as_uint(r) >> 16);
}

// ---------------------------------------------------------------------------
// Forward FC (known-good): out[r,c] = act(dot(X[r,:K], W[c,:K]) + b[c])
// ---------------------------------------------------------------------------
template<int K, int COLS, bool SIG>
__global__ __launch_bounds__(256)
void fc_kernel(const float* __restrict__ X, const float* __restrict__ W,
               const float* __restrict__ bias, float* __restrict__ Cout,
               float* __restrict__ Sout) {
    int idx = blockIdx.x * 256 + threadIdx.x;
    int r = idx / COLS, c = idx % COLS;
    const float4* xr = (const float4*)(X + (long)r * K);
    const float4* wr = (const float4*)(W + (long)c * K);
    float acc = 0.f;
#pragma unroll 4
    for (int k = 0; k < K / 4; k++) {
        float4 a = xr[k], b = wr[k];
        acc += a.x * b.x + a.y * b.y + a.z * b.z + a.w * b.w;
    }
    acc += bias[c];
    if (SIG) {
        float cv = sigm(acc);
        Cout[idx] = cv;
        Sout[idx] = cv * (1.f - cv);
    } else {
        Cout[idx] = acc;
    }
}

// ---------------------------------------------------------------------------
// One-time shared prep:
//   W1t h/l [1024][512] = split(W1^T)   (k-contiguous A operand of R-gemm)
//   W4  h/l [1024][512] = split(W4)     (k-contiguous A operand of L-gemm)
//   W3t fp32 [128][512] = W3^T          (so prep_batch reads coalesced)
// idx over [1024][512].
// ---------------------------------------------------------------------------
__global__ __launch_bounds__(256)
void prep_shared(const float* __restrict__ W1, const float* __restrict__ W4,
                 const float* __restrict__ W3,
                 unsigned short* __restrict__ W1th, unsigned short* __restrict__ W1tl,
                 unsigned short* __restrict__ W4h,  unsigned short* __restrict__ W4l,
                 float* __restrict__ W3t) {
    int idx = blockIdx.x * 256 + threadIdx.x;
    int d = idx >> 9, j = idx & 511;
    unsigned short h, l;
    bsplit(W1[(long)j * ND + d], h, l);   // W1 [512][1024], col d
    W1th[idx] = h; W1tl[idx] = l;
    bsplit(W4[idx], h, l);                // W4 [1024][512], direct
    W4h[idx] = h; W4l[idx] = l;
    if (idx < NH2 * NH1) {                // W3 [512][128] -> W3t [128][512]
        int i = idx >> 9, jj = idx & 511;
        W3t[idx] = W3[(long)jj * NH2 + i];
    }
}

// ---------------------------------------------------------------------------
// Per-batch MFMA B operands ([n][k] layout, k-contiguous), k-scale absorbed:
//   Br[b][i][j] = W2[i][j]  * s1[b][j]
//   Bl[b][i][j] = W3t[i][j] * s3[b][j]
// idx over [NB][128][512]; all reads coalesced.
// ---------------------------------------------------------------------------
__global__ __launch_bounds__(256)
void prep_batch(const float* __restrict__ W2, const float* __restrict__ W3t,
                const float* __restrict__ s1, const float* __restrict__ s3,
                unsigned short* __restrict__ Brh, unsigned short* __restrict__ Brl,
                unsigned short* __restrict__ Blh, unsigned short* __restrict__ Bll) {
    long idx = (long)blockIdx.x * 256 + threadIdx.x;
    int j = idx & 511;
    int b = idx >> 16;
    int ij = idx & 0xFFFF;                 // i*512 + j
    float s1v = s1[(long)b * NH1 + j];
    float s3v = s3[(long)b * NH1 + j];
    unsigned short h, l;
    bsplit(W2[ij] * s1v, h, l);
    Brh[idx] = h; Brl[idx] = l;
    bsplit(W3t[ij] * s3v, h, l);
    Blh[idx] = h; Bll[idx] = l;
}

// ---------------------------------------------------------------------------
// Fused bf16x3 MFMA GEMM pair, M=1024, N=128, K=512 per (batch, side):
//   side 0: R^T[b] = W1t @ Br[b]^T            -> Rh/Rl [b][1024][128]
//   side 1: L  [b] = (W4 @ Bl[b]^T) .* s2[b]  -> Lh/Ll [b][1024][128]
// Batch->XCD affinity: block g -> XCD g&7 (round-robin dispatch), batch
// b = (g&7) + 8*lb so each batch's B operand stays in ONE XCD's L2.
// Block: 256 thr = 4 waves (2x2), 128x128 tile; wave 64x64 = 4x4 MFMA tiles.
// mfma_f32_16x16x32_bf16 (m89): A lane holds A[l&15][8*(l>>4)+j];
// D: col = l&15, row = 4*(l>>4)+reg.
// ---------------------------------------------------------------------------
__global__ __launch_bounds__(256)
void mfma_nk2(const unsigned short* __restrict__ W1th, const unsigned short* __restrict__ W1tl,
              const unsigned short* __restrict__ W4h,  const unsigned short* __restrict__ W4l,
              const unsigned short* __restrict__ Brh,  const unsigned short* __restrict__ Brl,
              const unsigned short* __restrict__ Blh,  const unsigned short* __restrict__ Bll,
              const float* __restrict__ s2,
              unsigned short* __restrict__ Rh, unsigned short* __restrict__ Rl,
              unsigned short* __restrict__ Lh, unsigned short* __restrict__ Ll) {
    int g = blockIdx.x;                  // 2048 blocks
    int xcd = g & 7, seq = g >> 3;
    int lb = seq >> 4, inner = seq & 15;
    int b = xcd + 8 * lb;                // batch, pinned to XCD b%8
    int mt = inner & 7, side = inner >> 3;

    const unsigned short* Ah = side ? W4h : W1th;
    const unsigned short* Al = side ? W4l : W1tl;
    const unsigned short* Bhb = (side ? Blh : Brh) + (long)b * NH2 * NH1;
    const unsigned short* Blb = (side ? Bll : Brl) + (long)b * NH2 * NH1;
    unsigned short* Oh = (side ? Lh : Rh) + (long)b * ND * NH2;
    unsigned short* Ol = (side ? Ll : Rl) + (long)b * ND * NH2;

    int t = threadIdx.x;
    int lane = t & 63, w = t >> 6;
    int wr = w >> 1, wc = w & 1;
    int m0 = mt * 128 + wr * 64;
    int n0 = wc * 64;
    int lrow = lane & 15;
    int lk   = (lane >> 4) << 3;

    f32x4 zero = {0.f, 0.f, 0.f, 0.f};
    f32x4 acc[4][4];
#pragma unroll
    for (int i = 0; i < 4; i++)
#pragma unroll
        for (int j = 0; j < 4; j++) acc[i][j] = zero;

#pragma unroll 2
    for (int kc = 0; kc < NH1; kc += 32) {
        short8 ah[4], al[4], bh[4], bl[4];
#pragma unroll
        for (int i = 0; i < 4; i++) {
            long ao = (long)(m0 + i * 16 + lrow) * NH1 + kc + lk;
            ah[i] = *(const short8*)(Ah + ao);
            al[i] = *(const short8*)(Al + ao);
            long bo = (long)(n0 + i * 16 + lrow) * NH1 + kc + lk;
            bh[i] = *(const short8*)(Bhb + bo);
            bl[i] = *(const short8*)(Blb + bo);
        }
#pragma unroll
        for (int i = 0; i < 4; i++)
#pragma unroll
            for (int j = 0; j < 4; j++) {
                acc[i][j] = __builtin_amdgcn_mfma_f32_16x16x32_bf16(ah[i], bh[j], acc[i][j], 0, 0, 0);
                acc[i][j] = __builtin_amdgcn_mfma_f32_16x16x32_bf16(ah[i], bl[j], acc[i][j], 0, 0, 0);
                acc[i][j] = __builtin_amdgcn_mfma_f32_16x16x32_bf16(al[i], bh[j], acc[i][j], 0, 0, 0);
            }
    }

    float nsc[4] = {1.f, 1.f, 1.f, 1.f};
    if (side) {
#pragma unroll
        for (int j = 0; j < 4; j++) nsc[j] = s2[(long)b * NH2 + n0 + j * 16 + lrow];
    }
    int rbase = (lane >> 4) << 2;
#pragma unroll
    for (int i = 0; i < 4; i++)
#pragma unroll
        for (int r = 0; r < 4; r++) {
            long row = m0 + i * 16 + rbase + r;
#pragma unroll
            for (int j = 0; j < 4; j++) {
                float v = acc[i][j][r] * nsc[j];
                unsigned short h, l;
                bsplit(v, h, l);
                long off = row * NH2 + n0 + j * 16 + lrow;
                Oh[off] = h;
                Ol[off] = l;
            }
        }
}

// ---------------------------------------------------------------------------
// Jac[b] = L[b] @ R[b] via bf16x3 MFMA. M=N=1024, K=128.
// L [m][k], R^T [n][k], both k-contiguous -> every fragment is one 16B load.
// Batch->XCD affinity swizzle: all 64 blocks of batch b land on XCD b%8, so
// the batch's 1 MB L/R working set is fetched from HBM once into one L2.
// Epilogue: wave-local LDS transpose (padded, conflict-free) -> 16 coalesced
// nontemporal dwordx4 stores/lane (vs 64 scattered dword stores).
// ---------------------------------------------------------------------------
__global__ __launch_bounds__(256)
void jac_mfma(const unsigned short* __restrict__ Lh, const unsigned short* __restrict__ Ll,
              const unsigned short* __restrict__ Rh, const unsigned short* __restrict__ Rl,
              float* __restrict__ J) {
    int g = blockIdx.x;                  // 8192 blocks
    int xcd = g & 7, seq = g >> 3;
    int lb = seq >> 6, inner = seq & 63;
    int b = xcd + 8 * lb;                // batch, pinned to XCD b%8
    int bx = inner & 7, by = inner >> 3;

    long base = (long)b * ((long)ND * NH2);
    const unsigned short* Lhb = Lh + base;
    const unsigned short* Llb = Ll + base;
    const unsigned short* Rhb = Rh + base;
    const unsigned short* Rlb = Rl + base;

    int t = threadIdx.x;
    int lane = t & 63, w = t >> 6;
    int wr = w >> 1, wc = w & 1;
    int m0 = by * 128 + wr * 64;
    int n0 = bx * 128 + wc * 64;
    int lrow = lane & 15;
    int lk   = (lane >> 4) << 3;

    f32x4 zero = {0.f, 0.f, 0.f, 0.f};
    f32x4 acc[4][4];
#pragma unroll
    for (int i = 0; i < 4; i++)
#pragma unroll
        for (int j = 0; j < 4; j++) acc[i][j] = zero;

#pragma unroll
    for (int kc = 0; kc < NH2; kc += 32) {
        short8 ah[4], al[4], bh[4], bl[4];
#pragma unroll
        for (int i = 0; i < 4; i++) {
            long ao = (long)(m0 + i * 16 + lrow) * NH2 + kc + lk;
            ah[i] = *(const short8*)(Lhb + ao);
            al[i] = *(const short8*)(Llb + ao);
            long bo = (long)(n0 + i * 16 + lrow) * NH2 + kc + lk;
            bh[i] = *(const short8*)(Rhb + bo);
            bl[i] = *(const short8*)(Rlb + bo);
        }
#pragma unroll
        for (int i = 0; i < 4; i++)
#pragma unroll
            for (int j = 0; j < 4; j++) {
                acc[i][j] = __builtin_amdgcn_mfma_f32_16x16x32_bf16(ah[i], bh[j], acc[i][j], 0, 0, 0);
                acc[i][j] = __builtin_amdgcn_mfma_f32_16x16x32_bf16(ah[i], bl[j], acc[i][j], 0, 0, 0);
                acc[i][j] = __builtin_amdgcn_mfma_f32_16x16x32_bf16(al[i], bh[j], acc[i][j], 0, 0, 0);
            }
    }

    // Epilogue: per-wave 16x64 slice through padded LDS, then vec4 stores.
    // Pad 68: write banks (16*hi + ...) -> only 2-way alias (free, m136);
    // read banks spread across all 32. Intra-wave exchange only -> no barrier
    // (compiler orders ds_write -> ds_read via lgkmcnt).
    __shared__ float st[4][16][68];
    float* Jb = J + (long)b * ND * ND;
    int rbase = (lane >> 4) << 2;
#pragma unroll
    for (int i = 0; i < 4; i++) {
#pragma unroll
        for (int j = 0; j < 4; j++)
#pragma unroll
            for (int r = 0; r < 4; r++)
                st[w][rbase + r][j * 16 + lrow] = acc[i][j][r];
#pragma unroll
        for (int q = 0; q < 4; q++) {
            int row  = (lane >> 4) * 4 + q;
            int col4 = (lane & 15) * 4;
            f32x4 v = *(const f32x4*)&st[w][row][col4];
            long off = (long)(m0 + i * 16 + row) * ND + n0 + col4;
            __builtin_nontemporal_store(v, (f32x4*)(Jb + off));
        }
    }
}

extern "C" void kernel_launch(void* const* d_in, const int* in_sizes, int n_in,
                              void* d_out, int out_size, void* d_ws, size_t ws_size,
                              hipStream_t stream) {
    const float* x  = (const float*)d_in[0];
    const float* W1 = (const float*)d_in[1];
    const float* b1 = (const float*)d_in[2];
    const float* W2 = (const float*)d_in[3];
    const float* b2 = (const float*)d_in[4];
    const float* W3 = (const float*)d_in[5];
    const float* b3 = (const float*)d_in[6];
    const float* W4 = (const float*)d_in[7];
    const float* b4 = (const float*)d_in[8];

    // Output layout: recover [128*1024] | c2 [128*128] | Jac [128*1024*1024]
    float* out_rec = (float*)d_out;
    float* out_c2  = out_rec + NB * ND;
    float* out_jac = out_c2 + NB * NH2;

    // Workspace: fp32 c1,s1,s2,c3,s3,W3t | ushort splits
    float* ws = (float*)d_ws;
    float* c1  = ws;                      // 65536
    float* s1  = c1 + NB * NH1;           // 65536
    float* s2  = s1 + NB * NH1;           // 16384
    float* c3  = s2 + NB * NH2;           // 65536
    float* s3  = c3 + NB * NH1;           // 65536
    float* W3t = s3 + NB * NH1;           // 65536
    unsigned short* us = (unsigned short*)(W3t + NH2 * NH1);
    unsigned short* W1th = us;                          // 524288 each
    unsigned short* W1tl = W1th + (long)ND * NH1;
    unsigned short* W4h  = W1tl + (long)ND * NH1;
    unsigned short* W4l  = W4h  + (long)ND * NH1;
    unsigned short* Brh  = W4l  + (long)ND * NH1;       // 8388608 each
    unsigned short* Brl  = Brh  + (long)NB * NH2 * NH1;
    unsigned short* Blh  = Brl  + (long)NB * NH2 * NH1;
    unsigned short* Bll  = Blh  + (long)NB * NH2 * NH1;
    unsigned short* Lh   = Bll  + (long)NB * NH2 * NH1; // 16777216 each
    unsigned short* Ll   = Lh   + (long)NB * ND * NH2;
    unsigned short* Rh   = Ll   + (long)NB * ND * NH2;
    unsigned short* Rl   = Rh   + (long)NB * ND * NH2;

    // Forward pass (stores c & s = c*(1-c))
    fc_kernel<ND,  NH1, true ><<<NB * NH1 / 256, 256, 0, stream>>>(x,       W1, b1, c1,      s1);
    fc_kernel<NH1, NH2, true ><<<NB * NH2 / 256, 256, 0, stream>>>(c1,      W2, b2, out_c2,  s2);
    fc_kernel<NH2, NH1, true ><<<NB * NH1 / 256, 256, 0, stream>>>(out_c2,  W3, b3, c3,      s3);
    fc_kernel<NH1, ND,  false><<<NB * ND  / 256, 256, 0, stream>>>(c3,      W4, b4, out_rec, nullptr);

    // One-time bf16 splits of shared A operands (W1^T, W4) + W3^T fp32
    prep_shared<<<ND * NH1 / 256, 256, 0, stream>>>(W1, W4, W3, W1th, W1tl, W4h, W4l, W3t);

    // Per-batch k-scaled B operands (W2.*s1, W3t.*s3), fully coalesced
    prep_batch<<<(long)NB * NH2 * NH1 / 256, 256, 0, stream>>>(
        W2, W3t, s1, s3, Brh, Brl, Blh, Bll);

    // Fused R^T / L GEMMs: M=1024, N=128, K=512 per (batch, side)
    mfma_nk2<<<2048, 256, 0, stream>>>(
        W1th, W1tl, W4h, W4l, Brh, Brl, Blh, Bll, s2, Rh, Rl, Lh, Ll);

    // Jac[b] = L[b] @ R[b] : M=N=1024, K=128, bf16x3 MFMA, XCD-affine
    jac_mfma<<<8192, 256, 0, stream>>>(Lh, Ll, Rh, Rl, out_jac);
}

// Round 4
// 962.601 us; speedup vs baseline: 1.4745x; 1.0961x over previous
//
#include <hip/hip_runtime.h>

// Sizes (fixed by the problem)
#define NB  128
#define ND  1024
#define NH1 512
#define NH2 128

typedef __attribute__((ext_vector_type(8))) short    short8;  // 8 x bf16 (4 VGPRs)
typedef __attribute__((ext_vector_type(8))) _Float16 half8;   // 8 x f16  (4 VGPRs)
typedef __attribute__((ext_vector_type(4))) float    f32x4;   // MFMA accumulator / vec store

__device__ __forceinline__ float sigm(float v) { return 1.0f / (1.0f + __expf(-v)); }

// Split fp32 into bf16 hi + bf16 lo (lo compensates hi's truncation error).
__device__ __forceinline__ void bsplit(float v, unsigned short& h, unsigned short& l) {
    unsigned hu = __float_as_uint(v) & 0xffff0000u;
    h = (unsigned short)(hu >> 16);
    float r = v - __uint_as_float(hu);
    l = (unsigned short)(__float_as_uint(r) >> 16);
}

// ---------------------------------------------------------------------------
// Forward FC, split-K x4: 4 consecutive lanes share one output (quarter-K
// each), __shfl_xor quad-reduce, lane sub==0 applies bias/sigmoid + writes.
// 4x the blocks of the old one-thread-per-output version (fc2: 64->256).
// ---------------------------------------------------------------------------
template<int K, int COLS, bool SIG>
__global__ __launch_bounds__(256)
void fc_kernel(const float* __restrict__ X, const float* __restrict__ W,
               const float* __restrict__ bias, float* __restrict__ Cout,
               float* __restrict__ Sout) {
    int idx4 = blockIdx.x * 256 + threadIdx.x;
    int out = idx4 >> 2, sub = idx4 & 3;
    int r = out / COLS, c = out % COLS;
    constexpr int KQ = K / 4;            // floats per sub-chunk
    const float4* xr = (const float4*)(X + (long)r * K + sub * KQ);
    const float4* wr = (const float4*)(W + (long)c * K + sub * KQ);
    float acc = 0.f;
#pragma unroll 4
    for (int k = 0; k < KQ / 4; k++) {
        float4 a = xr[k], b = wr[k];
        acc += a.x * b.x + a.y * b.y + a.z * b.z + a.w * b.w;
    }
    acc += __shfl_xor(acc, 1, 64);
    acc += __shfl_xor(acc, 2, 64);
    if (sub == 0) {
        acc += bias[c];
        if (SIG) {
            float cv = sigm(acc);
            Cout[out] = cv;
            Sout[out] = cv * (1.f - cv);
        } else {
            Cout[out] = acc;
        }
    }
}

// ---------------------------------------------------------------------------
// One-time shared prep:
//   W1t16 [1024][512] = f16(W1^T)   (k-contiguous A operand of R-gemm)
//   W4_16 [1024][512] = f16(W4)     (k-contiguous A operand of L-gemm)
//   W3t fp32 [128][512] = W3^T      (so prep_batch reads coalesced)
// ---------------------------------------------------------------------------
__global__ __launch_bounds__(256)
void prep_shared(const float* __restrict__ W1, const float* __restrict__ W4,
                 const float* __restrict__ W3,
                 _Float16* __restrict__ W1t16, _Float16* __restrict__ W4_16,
                 float* __restrict__ W3t) {
    int idx = blockIdx.x * 256 + threadIdx.x;
    int d = idx >> 9, j = idx & 511;
    W1t16[idx] = (_Float16)W1[(long)j * ND + d];   // W1 [512][1024], col d
    W4_16[idx] = (_Float16)W4[idx];                // W4 [1024][512], direct
    if (idx < NH2 * NH1) {                         // W3 [512][128] -> W3t [128][512]
        int i = idx >> 9, jj = idx & 511;
        W3t[idx] = W3[(long)jj * NH2 + i];
    }
}

// ---------------------------------------------------------------------------
// Per-batch f16 MFMA B operands ([n][k] layout, k-contiguous), k-scale folded:
//   Br[b][i][j] = f16(W2[i][j]  * s1[b][j])
//   Bl[b][i][j] = f16(W3t[i][j] * s3[b][j])
// idx over [NB][128][512]; all reads/writes coalesced.
// ---------------------------------------------------------------------------
__global__ __launch_bounds__(256)
void prep_batch(const float* __restrict__ W2, const float* __restrict__ W3t,
                const float* __restrict__ s1, const float* __restrict__ s3,
                _Float16* __restrict__ Br, _Float16* __restrict__ Bl) {
    long idx = (long)blockIdx.x * 256 + threadIdx.x;
    int j = idx & 511;
    int b = idx >> 16;
    int ij = idx & 0xFFFF;                 // i*512 + j
    float s1v = s1[(long)b * NH1 + j];
    float s3v = s3[(long)b * NH1 + j];
    Br[idx] = (_Float16)(W2[ij] * s1v);
    Bl[idx] = (_Float16)(W3t[ij] * s3v);
}

// ---------------------------------------------------------------------------
// Fused single-pass f16 MFMA GEMM pair, M=1024, N=128, K=512 per (batch,side):
//   side 0: R^T[b] = W1t @ Br[b]^T            -> Rh/Rl [b][1024][128]
//   side 1: L  [b] = (W4 @ Bl[b]^T) .* s2[b]  -> Lh/Ll [b][1024][128]
// fp32 accumulate; output written as bf16 hi/lo split (jac input precision).
// Batch->XCD affinity: block g -> XCD g&7, batch b = (g&7) + 8*lb.
// Block: 256 thr = 4 waves (2x2), 128x128 tile; wave 64x64 = 4x4 MFMA tiles.
// ---------------------------------------------------------------------------
__global__ __launch_bounds__(256)
void mfma_nk2(const _Float16* __restrict__ A0, const _Float16* __restrict__ A1,
              const _Float16* __restrict__ Br, const _Float16* __restrict__ Bl,
              const float* __restrict__ s2,
              unsigned short* __restrict__ Rh, unsigned short* __restrict__ Rl,
              unsigned short* __restrict__ Lh, unsigned short* __restrict__ Ll) {
    int g = blockIdx.x;                  // 2048 blocks
    int xcd = g & 7, seq = g >> 3;
    int lb = seq >> 4, inner = seq & 15;
    int b = xcd + 8 * lb;                // batch, pinned to XCD b%8
    int mt = inner & 7, side = inner >> 3;

    const _Float16* A  = side ? A1 : A0;
    const _Float16* Bb = (side ? Bl : Br) + (long)b * NH2 * NH1;
    unsigned short* Oh = (side ? Lh : Rh) + (long)b * ND * NH2;
    unsigned short* Ol = (side ? Ll : Rl) + (long)b * ND * NH2;

    int t = threadIdx.x;
    int lane = t & 63, w = t >> 6;
    int wr = w >> 1, wc = w & 1;
    int m0 = mt * 128 + wr * 64;
    int n0 = wc * 64;
    int lrow = lane & 15;
    int lk   = (lane >> 4) << 3;

    f32x4 zero = {0.f, 0.f, 0.f, 0.f};
    f32x4 acc[4][4];
#pragma unroll
    for (int i = 0; i < 4; i++)
#pragma unroll
        for (int j = 0; j < 4; j++) acc[i][j] = zero;

#pragma unroll 2
    for (int kc = 0; kc < NH1; kc += 32) {
        half8 av[4], bv[4];
#pragma unroll
        for (int i = 0; i < 4; i++) {
            av[i] = *(const half8*)(A  + (long)(m0 + i * 16 + lrow) * NH1 + kc + lk);
            bv[i] = *(const half8*)(Bb + (long)(n0 + i * 16 + lrow) * NH1 + kc + lk);
        }
#pragma unroll
        for (int i = 0; i < 4; i++)
#pragma unroll
            for (int j = 0; j < 4; j++)
                acc[i][j] = __builtin_amdgcn_mfma_f32_16x16x32_f16(av[i], bv[j], acc[i][j], 0, 0, 0);
    }

    float nsc[4] = {1.f, 1.f, 1.f, 1.f};
    if (side) {
#pragma unroll
        for (int j = 0; j < 4; j++) nsc[j] = s2[(long)b * NH2 + n0 + j * 16 + lrow];
    }
    int rbase = (lane >> 4) << 2;
#pragma unroll
    for (int i = 0; i < 4; i++)
#pragma unroll
        for (int r = 0; r < 4; r++) {
            long row = m0 + i * 16 + rbase + r;
#pragma unroll
            for (int j = 0; j < 4; j++) {
                float v = acc[i][j][r] * nsc[j];
                unsigned short h, l;
                bsplit(v, h, l);
                long off = row * NH2 + n0 + j * 16 + lrow;
                Oh[off] = h;
                Ol[off] = l;
            }
        }
}

// ---------------------------------------------------------------------------
// Jac[b] = L[b] @ R[b] via bf16x3 MFMA (proven path, unchanged).
// M=N=1024, K=128; L [m][k], R^T [n][k], both k-contiguous.
// Batch->XCD affinity keeps each batch's 1 MB L/R set in one L2.
// Epilogue: wave-local padded-LDS transpose -> 16 coalesced NT dwordx4/lane.
// ---------------------------------------------------------------------------
__global__ __launch_bounds__(256)
void jac_mfma(const unsigned short* __restrict__ Lh, const unsigned short* __restrict__ Ll,
              const unsigned short* __restrict__ Rh, const unsigned short* __restrict__ Rl,
              float* __restrict__ J) {
    int g = blockIdx.x;                  // 8192 blocks
    int xcd = g & 7, seq = g >> 3;
    int lb = seq >> 6, inner = seq & 63;
    int b = xcd + 8 * lb;                // batch, pinned to XCD b%8
    int bx = inner & 7, by = inner >> 3;

    long base = (long)b * ((long)ND * NH2);
    const unsigned short* Lhb = Lh + base;
    const unsigned short* Llb = Ll + base;
    const unsigned short* Rhb = Rh + base;
    const unsigned short* Rlb = Rl + base;

    int t = threadIdx.x;
    int lane = t & 63, w = t >> 6;
    int wr = w >> 1, wc = w & 1;
    int m0 = by * 128 + wr * 64;
    int n0 = bx * 128 + wc * 64;
    int lrow = lane & 15;
    int lk   = (lane >> 4) << 3;

    f32x4 zero = {0.f, 0.f, 0.f, 0.f};
    f32x4 acc[4][4];
#pragma unroll
    for (int i = 0; i < 4; i++)
#pragma unroll
        for (int j = 0; j < 4; j++) acc[i][j] = zero;

#pragma unroll
    for (int kc = 0; kc < NH2; kc += 32) {
        short8 ah[4], al[4], bh[4], bl[4];
#pragma unroll
        for (int i = 0; i < 4; i++) {
            long ao = (long)(m0 + i * 16 + lrow) * NH2 + kc + lk;
            ah[i] = *(const short8*)(Lhb + ao);
            al[i] = *(const short8*)(Llb + ao);
            long bo = (long)(n0 + i * 16 + lrow) * NH2 + kc + lk;
            bh[i] = *(const short8*)(Rhb + bo);
            bl[i] = *(const short8*)(Rlb + bo);
        }
#pragma unroll
        for (int i = 0; i < 4; i++)
#pragma unroll
            for (int j = 0; j < 4; j++) {
                acc[i][j] = __builtin_amdgcn_mfma_f32_16x16x32_bf16(ah[i], bh[j], acc[i][j], 0, 0, 0);
                acc[i][j] = __builtin_amdgcn_mfma_f32_16x16x32_bf16(ah[i], bl[j], acc[i][j], 0, 0, 0);
                acc[i][j] = __builtin_amdgcn_mfma_f32_16x16x32_bf16(al[i], bh[j], acc[i][j], 0, 0, 0);
            }
    }

    // Epilogue: per-wave 16x64 slice through padded LDS, then vec4 NT stores.
    __shared__ float st[4][16][68];
    float* Jb = J + (long)b * ND * ND;
    int rbase = (lane >> 4) << 2;
#pragma unroll
    for (int i = 0; i < 4; i++) {
#pragma unroll
        for (int j = 0; j < 4; j++)
#pragma unroll
            for (int r = 0; r < 4; r++)
                st[w][rbase + r][j * 16 + lrow] = acc[i][j][r];
#pragma unroll
        for (int q = 0; q < 4; q++) {
            int row  = (lane >> 4) * 4 + q;
            int col4 = (lane & 15) * 4;
            f32x4 v = *(const f32x4*)&st[w][row][col4];
            long off = (long)(m0 + i * 16 + row) * ND + n0 + col4;
            __builtin_nontemporal_store(v, (f32x4*)(Jb + off));
        }
    }
}

extern "C" void kernel_launch(void* const* d_in, const int* in_sizes, int n_in,
                              void* d_out, int out_size, void* d_ws, size_t ws_size,
                              hipStream_t stream) {
    const float* x  = (const float*)d_in[0];
    const float* W1 = (const float*)d_in[1];
    const float* b1 = (const float*)d_in[2];
    const float* W2 = (const float*)d_in[3];
    const float* b2 = (const float*)d_in[4];
    const float* W3 = (const float*)d_in[5];
    const float* b3 = (const float*)d_in[6];
    const float* W4 = (const float*)d_in[7];
    const float* b4 = (const float*)d_in[8];

    // Output layout: recover [128*1024] | c2 [128*128] | Jac [128*1024*1024]
    float* out_rec = (float*)d_out;
    float* out_c2  = out_rec + NB * ND;
    float* out_jac = out_c2 + NB * NH2;

    // Workspace: fp32 c1,s1,s2,c3,s3,W3t | f16 W1t16,W4_16,Br,Bl | bf16 L/R h+l
    float* ws = (float*)d_ws;
    float* c1  = ws;                      // 65536
    float* s1  = c1 + NB * NH1;           // 65536
    float* s2  = s1 + NB * NH1;           // 16384
    float* c3  = s2 + NB * NH2;           // 65536
    float* s3  = c3 + NB * NH1;           // 65536
    float* W3t = s3 + NB * NH1;           // 65536
    _Float16* W1t16 = (_Float16*)(W3t + NH2 * NH1);     // 524288 each
    _Float16* W4_16 = W1t16 + (long)ND * NH1;
    _Float16* Br    = W4_16 + (long)ND * NH1;           // 8388608 each
    _Float16* Bl    = Br    + (long)NB * NH2 * NH1;
    unsigned short* Lh = (unsigned short*)(Bl + (long)NB * NH2 * NH1);  // 16777216 each
    unsigned short* Ll = Lh + (long)NB * ND * NH2;
    unsigned short* Rh = Ll + (long)NB * ND * NH2;
    unsigned short* Rl = Rh + (long)NB * ND * NH2;

    // Forward pass, split-K x4 (stores c & s = c*(1-c))
    fc_kernel<ND,  NH1, true ><<<NB * NH1 * 4 / 256, 256, 0, stream>>>(x,       W1, b1, c1,      s1);
    fc_kernel<NH1, NH2, true ><<<NB * NH2 * 4 / 256, 256, 0, stream>>>(c1,      W2, b2, out_c2,  s2);
    fc_kernel<NH2, NH1, true ><<<NB * NH1 * 4 / 256, 256, 0, stream>>>(out_c2,  W3, b3, c3,      s3);
    fc_kernel<NH1, ND,  false><<<NB * ND  * 4 / 256, 256, 0, stream>>>(c3,      W4, b4, out_rec, nullptr);

    // One-time f16 casts of shared A operands (W1^T, W4) + W3^T fp32
    prep_shared<<<ND * NH1 / 256, 256, 0, stream>>>(W1, W4, W3, W1t16, W4_16, W3t);

    // Per-batch k-scaled f16 B operands (W2.*s1, W3t.*s3), fully coalesced
    prep_batch<<<(long)NB * NH2 * NH1 / 256, 256, 0, stream>>>(
        W2, W3t, s1, s3, Br, Bl);

    // Fused R^T / L GEMMs: M=1024, N=128, K=512 per (batch, side), f16 x1
    mfma_nk2<<<2048, 256, 0, stream>>>(
        W1t16, W4_16, Br, Bl, s2, Rh, Rl, Lh, Ll);

    // Jac[b] = L[b] @ R[b] : M=N=1024, K=128, bf16x3 MFMA, XCD-affine
    jac_mfma<<<8192, 256, 0, stream>>>(Lh, Ll, Rh, Rl, out_jac);
}

// Round 5
// 953.481 us; speedup vs baseline: 1.4886x; 1.0096x over previous
//
#include <hip/hip_runtime.h>

// Sizes (fixed by the problem)
#define NB  128
#define ND  1024
#define NH1 512
#define NH2 128

typedef __attribute__((ext_vector_type(8)))  short    short8;  // 8 x bf16 (4 VGPRs)
typedef __attribute__((ext_vector_type(8)))  _Float16 half8;   // 8 x f16  (4 VGPRs)
typedef __attribute__((ext_vector_type(4)))  _Float16 half4;   // 4 x f16  (8 B)
typedef __attribute__((ext_vector_type(4)))  float    f32x4;   // vec store
typedef __attribute__((ext_vector_type(16))) float    f32x16;  // 32x32 MFMA acc

__device__ __forceinline__ float sigm(float v) { return 1.0f / (1.0f + __expf(-v)); }

// Split fp32 into bf16 hi + bf16 lo (lo compensates hi's truncation error).
__device__ __forceinline__ void bsplit(float v, unsigned short& h, unsigned short& l) {
    unsigned hu = __float_as_uint(v) & 0xffff0000u;
    h = (unsigned short)(hu >> 16);
    float r = v - __uint_as_float(hu);
    l = (unsigned short)(__float_as_uint(r) >> 16);
}

// ---------------------------------------------------------------------------
// Forward FC body, split-K x SPLIT: SPLIT consecutive lanes share one output,
// __shfl_xor reduce, lane sub==0 applies bias/sigmoid + writes.
// ---------------------------------------------------------------------------
template<int K, int COLS, bool SIG, int SPLIT>
__device__ __forceinline__ void fc_body(int bid, const float* __restrict__ X,
        const float* __restrict__ W, const float* __restrict__ bias,
        float* __restrict__ Cout, float* __restrict__ Sout) {
    int idx = bid * 256 + (int)threadIdx.x;
    int out = idx / SPLIT, sub = idx % SPLIT;
    int r = out / COLS, c = out % COLS;
    constexpr int KQ = K / SPLIT;            // floats per sub-chunk
    const float4* xr = (const float4*)(X + (long)r * K + sub * KQ);
    const float4* wr = (const float4*)(W + (long)c * K + sub * KQ);
    float acc = 0.f;
#pragma unroll 4
    for (int k = 0; k < KQ / 4; k++) {
        float4 a = xr[k], b = wr[k];
        acc += a.x * b.x + a.y * b.y + a.z * b.z + a.w * b.w;
    }
#pragma unroll
    for (int o = 1; o < SPLIT; o <<= 1) acc += __shfl_xor(acc, o, 64);
    if (sub == 0) {
        acc += bias[c];
        if (SIG) {
            float cv = sigm(acc);
            Cout[out] = cv;
            Sout[out] = cv * (1.f - cv);
        } else {
            Cout[out] = acc;
        }
    }
}

template<int K, int COLS, bool SIG, int SPLIT>
__global__ __launch_bounds__(256)
void fc_kernel(const float* __restrict__ X, const float* __restrict__ W,
               const float* __restrict__ bias, float* __restrict__ Cout,
               float* __restrict__ Sout) {
    fc_body<K, COLS, SIG, SPLIT>(blockIdx.x, X, W, bias, Cout, Sout);
}

// ---------------------------------------------------------------------------
// fc1 fused with one-time shared prep (independent work, overlapped):
//   blocks [0,1024):    fc1 (x@W1 -> c1,s1), split-K x4
//   blocks [1024,3072): W1t16 = f16(W1^T), W4_16 = f16(W4), W3t = W3^T
// ---------------------------------------------------------------------------
__global__ __launch_bounds__(256)
void fc1_prep(const float* __restrict__ x,  const float* __restrict__ W1,
              const float* __restrict__ b1, float* __restrict__ c1,
              float* __restrict__ s1,
              const float* __restrict__ W4, const float* __restrict__ W3,
              _Float16* __restrict__ W1t16, _Float16* __restrict__ W4_16,
              float* __restrict__ W3t) {
    int bid = blockIdx.x;
    if (bid < NB * NH1 * 4 / 256) {
        fc_body<ND, NH1, true, 4>(bid, x, W1, b1, c1, s1);
    } else {
        int idx = (bid - NB * NH1 * 4 / 256) * 256 + (int)threadIdx.x;
        int d = idx >> 9, j = idx & 511;
        W1t16[idx] = (_Float16)W1[(long)j * ND + d];   // W1 [512][1024], col d
        W4_16[idx] = (_Float16)W4[idx];                // W4 [1024][512]
        if (idx < NH2 * NH1) {                         // W3 [512][128] -> W3t
            int i = idx >> 9, jj = idx & 511;
            W3t[idx] = W3[(long)jj * NH2 + i];
        }
    }
}

// ---------------------------------------------------------------------------
// fc4 fused with per-batch B-operand prep (both depend only on <=fc3):
//   blocks [0,2048):     recover = c3@W4^T + b4, split-K x4
//   blocks [2048,10240): Br[b][i][j] = f16(W2[i][j]*s1[b][j]),
//                        Bl[b][i][j] = f16(W3t[i][j]*s3[b][j]), vec x4
// ---------------------------------------------------------------------------
__global__ __launch_bounds__(256)
void fc4_prep(const float* __restrict__ c3, const float* __restrict__ W4,
              const float* __restrict__ b4, float* __restrict__ out_rec,
              const float* __restrict__ W2, const float* __restrict__ W3t,
              const float* __restrict__ s1, const float* __restrict__ s3,
              _Float16* __restrict__ Br, _Float16* __restrict__ Bl) {
    int bid = blockIdx.x;
    if (bid < NB * ND * 4 / 256) {
        fc_body<NH1, ND, false, 4>(bid, c3, W4, b4, out_rec, nullptr);
    } else {
        long idx = (long)(bid - NB * ND * 4 / 256) * 256 + threadIdx.x;
        int j4 = (int)(idx & 127) << 2;
        int i  = (int)(idx >> 7) & 127;
        int b  = (int)(idx >> 14);
        float4 wv = *(const float4*)(W2 + (long)i * NH1 + j4);
        float4 sv = *(const float4*)(s1 + (long)b * NH1 + j4);
        half4 o;
        o[0] = (_Float16)(wv.x * sv.x); o[1] = (_Float16)(wv.y * sv.y);
        o[2] = (_Float16)(wv.z * sv.z); o[3] = (_Float16)(wv.w * sv.w);
        *(half4*)(Br + idx * 4) = o;
        wv = *(const float4*)(W3t + (long)i * NH1 + j4);
        sv = *(const float4*)(s3  + (long)b * NH1 + j4);
        o[0] = (_Float16)(wv.x * sv.x); o[1] = (_Float16)(wv.y * sv.y);
        o[2] = (_Float16)(wv.z * sv.z); o[3] = (_Float16)(wv.w * sv.w);
        *(half4*)(Bl + idx * 4) = o;
    }
}

// ---------------------------------------------------------------------------
// Fused single-pass f16 MFMA GEMM pair (32x32x16), M=1024, N=128, K=512:
//   side 0: R^T[b] = W1t @ Br[b]^T            -> Rh/Rl [b][1024][128]
//   side 1: L  [b] = (W4 @ Bl[b]^T) .* s2[b]  -> Lh/Ll [b][1024][128]
// fp32 accumulate; output = bf16 hi/lo split (jac input precision).
// Batch->XCD affinity: block g -> XCD g&7, batch b = (g&7) + 8*lb.
// Block: 4 waves (2x2), 128x128 tile; wave 64x64 = 2x2 MFMA 32x32 tiles.
// 32x32 layouts (m74/m101): A lane holds A[l&31][8*(l>>5)+j];
// D: col = l&31, row = (reg&3)+8*(reg>>2)+4*(l>>5).
// ---------------------------------------------------------------------------
__global__ __launch_bounds__(256)
void mfma_nk2(const _Float16* __restrict__ A0, const _Float16* __restrict__ A1,
              const _Float16* __restrict__ Br, const _Float16* __restrict__ Bl,
              const float* __restrict__ s2,
              unsigned short* __restrict__ Rh, unsigned short* __restrict__ Rl,
              unsigned short* __restrict__ Lh, unsigned short* __restrict__ Ll) {
    int g = blockIdx.x;                  // 2048 blocks
    int xcd = g & 7, seq = g >> 3;
    int lb = seq >> 4, inner = seq & 15;
    int b = xcd + 8 * lb;                // batch, pinned to XCD b%8
    int mt = inner & 7, side = inner >> 3;

    const _Float16* A  = side ? A1 : A0;
    const _Float16* Bb = (side ? Bl : Br) + (long)b * NH2 * NH1;
    unsigned short* Oh = (side ? Lh : Rh) + (long)b * ND * NH2;
    unsigned short* Ol = (side ? Ll : Rl) + (long)b * ND * NH2;

    int t = threadIdx.x;
    int lane = t & 63, w = t >> 6;
    int wr = w >> 1, wc = w & 1;
    int m0 = mt * 128 + wr * 64;
    int n0 = wc * 64;
    int lrow = lane & 31;
    int lk   = (lane >> 5) << 3;

    f32x16 acc[2][2];
#pragma unroll
    for (int i = 0; i < 2; i++)
#pragma unroll
        for (int j = 0; j < 2; j++)
#pragma unroll
            for (int r = 0; r < 16; r++) acc[i][j][r] = 0.f;

#pragma unroll 2
    for (int kc = 0; kc < NH1; kc += 16) {
        half8 av[2], bv[2];
#pragma unroll
        for (int i = 0; i < 2; i++) {
            av[i] = *(const half8*)(A  + (long)(m0 + i * 32 + lrow) * NH1 + kc + lk);
            bv[i] = *(const half8*)(Bb + (long)(n0 + i * 32 + lrow) * NH1 + kc + lk);
        }
#pragma unroll
        for (int i = 0; i < 2; i++)
#pragma unroll
            for (int j = 0; j < 2; j++)
                acc[i][j] = __builtin_amdgcn_mfma_f32_32x32x16_f16(av[i], bv[j], acc[i][j], 0, 0, 0);
    }

    float nsc[2] = {1.f, 1.f};
    if (side) {
#pragma unroll
        for (int j = 0; j < 2; j++) nsc[j] = s2[(long)b * NH2 + n0 + j * 32 + lrow];
    }
    int hi4 = (lane >> 5) << 2;
#pragma unroll
    for (int i = 0; i < 2; i++)
#pragma unroll
        for (int j = 0; j < 2; j++)
#pragma unroll
            for (int r = 0; r < 16; r++) {
                int row = m0 + i * 32 + (r & 3) + 8 * (r >> 2) + hi4;
                float v = acc[i][j][r] * nsc[j];
                unsigned short h, l;
                bsplit(v, h, l);
                long off = (long)row * NH2 + n0 + j * 32 + lrow;
                Oh[off] = h;
                Ol[off] = l;
            }
}

// ---------------------------------------------------------------------------
// Jac[b] = L[b] @ R[b] via bf16x3 MFMA, 32x32x16 shape. M=N=1024, K=128.
// L [m][k], R^T [n][k], both k-contiguous -> every fragment one 16B load.
// Batch->XCD affinity keeps each batch's 1 MB L/R set in one L2.
// Epilogue: wave-local padded-LDS transpose -> coalesced NT dwordx4 stores.
// ---------------------------------------------------------------------------
__global__ __launch_bounds__(256)
void jac_mfma(const unsigned short* __restrict__ Lh, const unsigned short* __restrict__ Ll,
              const unsigned short* __restrict__ Rh, const unsigned short* __restrict__ Rl,
              float* __restrict__ J) {
    int g = blockIdx.x;                  // 8192 blocks
    int xcd = g & 7, seq = g >> 3;
    int lb = seq >> 6, inner = seq & 63;
    int b = xcd + 8 * lb;                // batch, pinned to XCD b%8
    int bx = inner & 7, by = inner >> 3;

    long base = (long)b * ((long)ND * NH2);
    const unsigned short* Lhb = Lh + base;
    const unsigned short* Llb = Ll + base;
    const unsigned short* Rhb = Rh + base;
    const unsigned short* Rlb = Rl + base;

    int t = threadIdx.x;
    int lane = t & 63, w = t >> 6;
    int wr = w >> 1, wc = w & 1;
    int m0 = by * 128 + wr * 64;
    int n0 = bx * 128 + wc * 64;
    int lrow = lane & 31;
    int lk   = (lane >> 5) << 3;

    f32x16 acc[2][2];
#pragma unroll
    for (int i = 0; i < 2; i++)
#pragma unroll
        for (int j = 0; j < 2; j++)
#pragma unroll
            for (int r = 0; r < 16; r++) acc[i][j][r] = 0.f;

#pragma unroll 4
    for (int kc = 0; kc < NH2; kc += 16) {
        short8 ah[2], al[2], bh[2], bl[2];
#pragma unroll
        for (int i = 0; i < 2; i++) {
            long ao = (long)(m0 + i * 32 + lrow) * NH2 + kc + lk;
            ah[i] = *(const short8*)(Lhb + ao);
            al[i] = *(const short8*)(Llb + ao);
            long bo = (long)(n0 + i * 32 + lrow) * NH2 + kc + lk;
            bh[i] = *(const short8*)(Rhb + bo);
            bl[i] = *(const short8*)(Rlb + bo);
        }
#pragma unroll
        for (int i = 0; i < 2; i++)
#pragma unroll
            for (int j = 0; j < 2; j++) {
                acc[i][j] = __builtin_amdgcn_mfma_f32_32x32x16_bf16(ah[i], bh[j], acc[i][j], 0, 0, 0);
                acc[i][j] = __builtin_amdgcn_mfma_f32_32x32x16_bf16(ah[i], bl[j], acc[i][j], 0, 0, 0);
                acc[i][j] = __builtin_amdgcn_mfma_f32_32x32x16_bf16(al[i], bh[j], acc[i][j], 0, 0, 0);
            }
    }

    // Epilogue: per-wave 32x64 slab through padded LDS, then vec4 NT stores.
    // Write banks: per reg, 2 lanes/bank (free); read: 2-way alias (free).
    __shared__ float st[4][32][68];
    float* Jb = J + (long)b * ND * ND;
    int hi4 = (lane >> 5) << 2;
#pragma unroll
    for (int i = 0; i < 2; i++) {
#pragma unroll
        for (int j = 0; j < 2; j++)
#pragma unroll
            for (int r = 0; r < 16; r++)
                st[w][(r & 3) + 8 * (r >> 2) + hi4][j * 32 + lrow] = acc[i][j][r];
#pragma unroll
        for (int q = 0; q < 8; q++) {
            int row  = q * 4 + (lane >> 4);
            int col4 = (lane & 15) * 4;
            f32x4 v = *(const f32x4*)&st[w][row][col4];
            long off = (long)(m0 + i * 32 + row) * ND + n0 + col4;
            __builtin_nontemporal_store(v, (f32x4*)(Jb + off));
        }
    }
}

extern "C" void kernel_launch(void* const* d_in, const int* in_sizes, int n_in,
                              void* d_out, int out_size, void* d_ws, size_t ws_size,
                              hipStream_t stream) {
    const float* x  = (const float*)d_in[0];
    const float* W1 = (const float*)d_in[1];
    const float* b1 = (const float*)d_in[2];
    const float* W2 = (const float*)d_in[3];
    const float* b2 = (const float*)d_in[4];
    const float* W3 = (const float*)d_in[5];
    const float* b3 = (const float*)d_in[6];
    const float* W4 = (const float*)d_in[7];
    const float* b4 = (const float*)d_in[8];

    // Output layout: recover [128*1024] | c2 [128*128] | Jac [128*1024*1024]
    float* out_rec = (float*)d_out;
    float* out_c2  = out_rec + NB * ND;
    float* out_jac = out_c2 + NB * NH2;

    // Workspace: fp32 c1,s1,s2,c3,s3,W3t | f16 W1t16,W4_16,Br,Bl | bf16 L/R h+l
    float* ws = (float*)d_ws;
    float* c1  = ws;                      // 65536
    float* s1  = c1 + NB * NH1;           // 65536
    float* s2  = s1 + NB * NH1;           // 16384
    float* c3  = s2 + NB * NH2;           // 65536
    float* s3  = c3 + NB * NH1;           // 65536
    float* W3t = s3 + NB * NH1;           // 65536
    _Float16* W1t16 = (_Float16*)(W3t + NH2 * NH1);     // 524288 each
    _Float16* W4_16 = W1t16 + (long)ND * NH1;
    _Float16* Br    = W4_16 + (long)ND * NH1;           // 8388608 each
    _Float16* Bl    = Br    + (long)NB * NH2 * NH1;
    unsigned short* Lh = (unsigned short*)(Bl + (long)NB * NH2 * NH1);  // 16777216 each
    unsigned short* Ll = Lh + (long)NB * ND * NH2;
    unsigned short* Rh = Ll + (long)NB * ND * NH2;
    unsigned short* Rl = Rh + (long)NB * ND * NH2;

    // fc1 + one-time shared prep (1024 fc blocks + 2048 prep blocks)
    fc1_prep<<<NB * NH1 * 4 / 256 + ND * NH1 / 256, 256, 0, stream>>>(
        x, W1, b1, c1, s1, W4, W3, W1t16, W4_16, W3t);

    // fc2, fc3: split-K x8 (low-parallelism links of the serial chain)
    fc_kernel<NH1, NH2, true, 8><<<NB * NH2 * 8 / 256, 256, 0, stream>>>(c1,     W2, b2, out_c2, s2);
    fc_kernel<NH2, NH1, true, 8><<<NB * NH1 * 8 / 256, 256, 0, stream>>>(out_c2, W3, b3, c3,     s3);

    // fc4 + per-batch B prep (2048 fc blocks + 8192 prep blocks)
    fc4_prep<<<NB * ND * 4 / 256 + (long)NB * NH2 * NH1 / 1024, 256, 0, stream>>>(
        c3, W4, b4, out_rec, W2, W3t, s1, s3, Br, Bl);

    // Fused R^T / L GEMMs: M=1024, N=128, K=512 per (batch, side), f16 32x32
    mfma_nk2<<<2048, 256, 0, stream>>>(
        W1t16, W4_16, Br, Bl, s2, Rh, Rl, Lh, Ll);

    // Jac[b] = L[b] @ R[b] : M=N=1024, K=128, bf16x3 32x32, XCD-affine
    jac_mfma<<<8192, 256, 0, stream>>>(Lh, Ll, Rh, Rl, out_jac);
}

// Round 6
// 841.039 us; speedup vs baseline: 1.6876x; 1.1337x over previous
//
#include <hip/hip_runtime.h>

// Sizes (fixed by the problem)
#define NB  128
#define ND  1024
#define NH1 512
#define NH2 128

typedef __attribute__((ext_vector_type(8)))  _Float16 half8;   // 8 x f16  (4 VGPRs)
typedef __attribute__((ext_vector_type(4)))  _Float16 half4;   // 4 x f16  (8 B)
typedef __attribute__((ext_vector_type(4)))  float    f32x4;   // vec store
typedef __attribute__((ext_vector_type(16))) float    f32x16;  // 32x32 MFMA acc

__device__ __forceinline__ float sigm(float v) { return 1.0f / (1.0f + __expf(-v)); }

// ---------------------------------------------------------------------------
// Forward FC body, split-K x SPLIT: SPLIT consecutive lanes share one output,
// __shfl_xor reduce, lane sub==0 applies bias/sigmoid + writes.
// ---------------------------------------------------------------------------
template<int K, int COLS, bool SIG, int SPLIT>
__device__ __forceinline__ void fc_body(int bid, const float* __restrict__ X,
        const float* __restrict__ W, const float* __restrict__ bias,
        float* __restrict__ Cout, float* __restrict__ Sout) {
    int idx = bid * 256 + (int)threadIdx.x;
    int out = idx / SPLIT, sub = idx % SPLIT;
    int r = out / COLS, c = out % COLS;
    constexpr int KQ = K / SPLIT;            // floats per sub-chunk
    const float4* xr = (const float4*)(X + (long)r * K + sub * KQ);
    const float4* wr = (const float4*)(W + (long)c * K + sub * KQ);
    float acc = 0.f;
#pragma unroll 4
    for (int k = 0; k < KQ / 4; k++) {
        float4 a = xr[k], b = wr[k];
        acc += a.x * b.x + a.y * b.y + a.z * b.z + a.w * b.w;
    }
#pragma unroll
    for (int o = 1; o < SPLIT; o <<= 1) acc += __shfl_xor(acc, o, 64);
    if (sub == 0) {
        acc += bias[c];
        if (SIG) {
            float cv = sigm(acc);
            Cout[out] = cv;
            Sout[out] = cv * (1.f - cv);
        } else {
            Cout[out] = acc;
        }
    }
}

template<int K, int COLS, bool SIG, int SPLIT>
__global__ __launch_bounds__(256)
void fc_kernel(const float* __restrict__ X, const float* __restrict__ W,
               const float* __restrict__ bias, float* __restrict__ Cout,
               float* __restrict__ Sout) {
    fc_body<K, COLS, SIG, SPLIT>(blockIdx.x, X, W, bias, Cout, Sout);
}

// ---------------------------------------------------------------------------
// fc1 fused with one-time shared prep (independent work, overlapped):
//   blocks [0,1024):    fc1 (x@W1 -> c1,s1), split-K x4
//   blocks [1024,3072): W1t16 = f16(W1^T), W4_16 = f16(W4), W3t = W3^T
// ---------------------------------------------------------------------------
__global__ __launch_bounds__(256)
void fc1_prep(const float* __restrict__ x,  const float* __restrict__ W1,
              const float* __restrict__ b1, float* __restrict__ c1,
              float* __restrict__ s1,
              const float* __restrict__ W4, const float* __restrict__ W3,
              _Float16* __restrict__ W1t16, _Float16* __restrict__ W4_16,
              float* __restrict__ W3t) {
    int bid = blockIdx.x;
    if (bid < NB * NH1 * 4 / 256) {
        fc_body<ND, NH1, true, 4>(bid, x, W1, b1, c1, s1);
    } else {
        int idx = (bid - NB * NH1 * 4 / 256) * 256 + (int)threadIdx.x;
        int d = idx >> 9, j = idx & 511;
        W1t16[idx] = (_Float16)W1[(long)j * ND + d];   // W1 [512][1024], col d
        W4_16[idx] = (_Float16)W4[idx];                // W4 [1024][512]
        if (idx < NH2 * NH1) {                         // W3 [512][128] -> W3t
            int i = idx >> 9, jj = idx & 511;
            W3t[idx] = W3[(long)jj * NH2 + i];
        }
    }
}

// ---------------------------------------------------------------------------
// fc4 fused with per-batch B-operand prep (both depend only on <=fc3):
//   blocks [0,2048):     recover = c3@W4^T + b4, split-K x4
//   blocks [2048,10240): Br[b][i][j] = f16(W2[i][j]*s1[b][j]),
//                        Bl[b][i][j] = f16(W3t[i][j]*s3[b][j]), vec x4
// ---------------------------------------------------------------------------
__global__ __launch_bounds__(256)
void fc4_prep(const float* __restrict__ c3, const float* __restrict__ W4,
              const float* __restrict__ b4, float* __restrict__ out_rec,
              const float* __restrict__ W2, const float* __restrict__ W3t,
              const float* __restrict__ s1, const float* __restrict__ s3,
              _Float16* __restrict__ Br, _Float16* __restrict__ Bl) {
    int bid = blockIdx.x;
    if (bid < NB * ND * 4 / 256) {
        fc_body<NH1, ND, false, 4>(bid, c3, W4, b4, out_rec, nullptr);
    } else {
        long idx = (long)(bid - NB * ND * 4 / 256) * 256 + threadIdx.x;
        int j4 = (int)(idx & 127) << 2;
        int i  = (int)(idx >> 7) & 127;
        int b  = (int)(idx >> 14);
        float4 wv = *(const float4*)(W2 + (long)i * NH1 + j4);
        float4 sv = *(const float4*)(s1 + (long)b * NH1 + j4);
        half4 o;
        o[0] = (_Float16)(wv.x * sv.x); o[1] = (_Float16)(wv.y * sv.y);
        o[2] = (_Float16)(wv.z * sv.z); o[3] = (_Float16)(wv.w * sv.w);
        *(half4*)(Br + idx * 4) = o;
        wv = *(const float4*)(W3t + (long)i * NH1 + j4);
        sv = *(const float4*)(s3  + (long)b * NH1 + j4);
        o[0] = (_Float16)(wv.x * sv.x); o[1] = (_Float16)(wv.y * sv.y);
        o[2] = (_Float16)(wv.z * sv.z); o[3] = (_Float16)(wv.w * sv.w);
        *(half4*)(Bl + idx * 4) = o;
    }
}

// ---------------------------------------------------------------------------
// Fused single-pass f16 MFMA GEMM pair (32x32x16), M=1024, N=128, K=512:
//   side 0: R^T[b] = W1t @ Br[b]^T            -> Rf [b][1024][128]
//   side 1: L  [b] = (W4 @ Bl[b]^T) .* s2[b]  -> Lf [b][1024][128]
// fp32 accumulate; output = single f16 (round-4 evidence: f16 single-pass
// on the K=512 GEMMs left absmax bit-identical at 0.125 -> same precision
// class is safe for the K=128 jac inputs).
// Batch->XCD affinity: block g -> XCD g&7, batch b = (g&7) + 8*lb.
// Block: 4 waves (2x2), 128x128 tile; wave 64x64 = 2x2 MFMA 32x32 tiles.
// 32x32 layouts (m74/m101): A lane holds A[l&31][8*(l>>5)+j];
// D: col = l&31, row = (reg&3)+8*(reg>>2)+4*(l>>5).
// ---------------------------------------------------------------------------
__global__ __launch_bounds__(256)
void mfma_nk2(const _Float16* __restrict__ A0, const _Float16* __restrict__ A1,
              const _Float16* __restrict__ Br, const _Float16* __restrict__ Bl,
              const float* __restrict__ s2,
              _Float16* __restrict__ Rf, _Float16* __restrict__ Lf) {
    int g = blockIdx.x;                  // 2048 blocks
    int xcd = g & 7, seq = g >> 3;
    int lb = seq >> 4, inner = seq & 15;
    int b = xcd + 8 * lb;                // batch, pinned to XCD b%8
    int mt = inner & 7, side = inner >> 3;

    const _Float16* A  = side ? A1 : A0;
    const _Float16* Bb = (side ? Bl : Br) + (long)b * NH2 * NH1;
    _Float16* O = (side ? Lf : Rf) + (long)b * ND * NH2;

    int t = threadIdx.x;
    int lane = t & 63, w = t >> 6;
    int wr = w >> 1, wc = w & 1;
    int m0 = mt * 128 + wr * 64;
    int n0 = wc * 64;
    int lrow = lane & 31;
    int lk   = (lane >> 5) << 3;

    f32x16 acc[2][2];
#pragma unroll
    for (int i = 0; i < 2; i++)
#pragma unroll
        for (int j = 0; j < 2; j++)
#pragma unroll
            for (int r = 0; r < 16; r++) acc[i][j][r] = 0.f;

#pragma unroll 2
    for (int kc = 0; kc < NH1; kc += 16) {
        half8 av[2], bv[2];
#pragma unroll
        for (int i = 0; i < 2; i++) {
            av[i] = *(const half8*)(A  + (long)(m0 + i * 32 + lrow) * NH1 + kc + lk);
            bv[i] = *(const half8*)(Bb + (long)(n0 + i * 32 + lrow) * NH1 + kc + lk);
        }
#pragma unroll
        for (int i = 0; i < 2; i++)
#pragma unroll
            for (int j = 0; j < 2; j++)
                acc[i][j] = __builtin_amdgcn_mfma_f32_32x32x16_f16(av[i], bv[j], acc[i][j], 0, 0, 0);
    }

    float nsc[2] = {1.f, 1.f};
    if (side) {
#pragma unroll
        for (int j = 0; j < 2; j++) nsc[j] = s2[(long)b * NH2 + n0 + j * 32 + lrow];
    }
    int hi4 = (lane >> 5) << 2;
#pragma unroll
    for (int i = 0; i < 2; i++)
#pragma unroll
        for (int j = 0; j < 2; j++)
#pragma unroll
            for (int r = 0; r < 16; r++) {
                int row = m0 + i * 32 + (r & 3) + 8 * (r >> 2) + hi4;
                O[(long)row * NH2 + n0 + j * 32 + lrow] =
                    (_Float16)(acc[i][j][r] * nsc[j]);
            }
}

// ---------------------------------------------------------------------------
// Jac[b] = L[b] @ R[b], single-pass f16 MFMA 32x32x16. M=N=1024, K=128.
// Lf [m][k], Rf^T [n][k], both k-contiguous -> every fragment one 16B load.
// Batch->XCD affinity keeps each batch's 0.5 MB L/R set in one L2.
// Epilogue: wave-local padded-LDS transpose -> coalesced NT dwordx4 stores.
// ---------------------------------------------------------------------------
__global__ __launch_bounds__(256)
void jac_mfma(const _Float16* __restrict__ Lf, const _Float16* __restrict__ Rf,
              float* __restrict__ J) {
    int g = blockIdx.x;                  // 8192 blocks
    int xcd = g & 7, seq = g >> 3;
    int lb = seq >> 6, inner = seq & 63;
    int b = xcd + 8 * lb;                // batch, pinned to XCD b%8
    int bx = inner & 7, by = inner >> 3;

    long base = (long)b * ((long)ND * NH2);
    const _Float16* Lb = Lf + base;
    const _Float16* Rb = Rf + base;

    int t = threadIdx.x;
    int lane = t & 63, w = t >> 6;
    int wr = w >> 1, wc = w & 1;
    int m0 = by * 128 + wr * 64;
    int n0 = bx * 128 + wc * 64;
    int lrow = lane & 31;
    int lk   = (lane >> 5) << 3;

    f32x16 acc[2][2];
#pragma unroll
    for (int i = 0; i < 2; i++)
#pragma unroll
        for (int j = 0; j < 2; j++)
#pragma unroll
            for (int r = 0; r < 16; r++) acc[i][j][r] = 0.f;

#pragma unroll
    for (int kc = 0; kc < NH2; kc += 16) {
        half8 av[2], bv[2];
#pragma unroll
        for (int i = 0; i < 2; i++) {
            av[i] = *(const half8*)(Lb + (long)(m0 + i * 32 + lrow) * NH2 + kc + lk);
            bv[i] = *(const half8*)(Rb + (long)(n0 + i * 32 + lrow) * NH2 + kc + lk);
        }
#pragma unroll
        for (int i = 0; i < 2; i++)
#pragma unroll
            for (int j = 0; j < 2; j++)
                acc[i][j] = __builtin_amdgcn_mfma_f32_32x32x16_f16(av[i], bv[j], acc[i][j], 0, 0, 0);
    }

    // Epilogue: per-wave 32x64 slab through padded LDS, then vec4 NT stores.
    __shared__ float st[4][32][68];
    float* Jb = J + (long)b * ND * ND;
    int hi4 = (lane >> 5) << 2;
#pragma unroll
    for (int i = 0; i < 2; i++) {
#pragma unroll
        for (int j = 0; j < 2; j++)
#pragma unroll
            for (int r = 0; r < 16; r++)
                st[w][(r & 3) + 8 * (r >> 2) + hi4][j * 32 + lrow] = acc[i][j][r];
#pragma unroll
        for (int q = 0; q < 8; q++) {
            int row  = q * 4 + (lane >> 4);
            int col4 = (lane & 15) * 4;
            f32x4 v = *(const f32x4*)&st[w][row][col4];
            long off = (long)(m0 + i * 32 + row) * ND + n0 + col4;
            __builtin_nontemporal_store(v, (f32x4*)(Jb + off));
        }
    }
}

extern "C" void kernel_launch(void* const* d_in, const int* in_sizes, int n_in,
                              void* d_out, int out_size, void* d_ws, size_t ws_size,
                              hipStream_t stream) {
    const float* x  = (const float*)d_in[0];
    const float* W1 = (const float*)d_in[1];
    const float* b1 = (const float*)d_in[2];
    const float* W2 = (const float*)d_in[3];
    const float* b2 = (const float*)d_in[4];
    const float* W3 = (const float*)d_in[5];
    const float* b3 = (const float*)d_in[6];
    const float* W4 = (const float*)d_in[7];
    const float* b4 = (const float*)d_in[8];

    // Output layout: recover [128*1024] | c2 [128*128] | Jac [128*1024*1024]
    float* out_rec = (float*)d_out;
    float* out_c2  = out_rec + NB * ND;
    float* out_jac = out_c2 + NB * NH2;

    // Workspace: fp32 c1,s1,s2,c3,s3,W3t | f16 W1t16,W4_16,Br,Bl,Lf,Rf
    float* ws = (float*)d_ws;
    float* c1  = ws;                      // 65536
    float* s1  = c1 + NB * NH1;           // 65536
    float* s2  = s1 + NB * NH1;           // 16384
    float* c3  = s2 + NB * NH2;           // 65536
    float* s3  = c3 + NB * NH1;           // 65536
    float* W3t = s3 + NB * NH1;           // 65536
    _Float16* W1t16 = (_Float16*)(W3t + NH2 * NH1);     // 524288 each
    _Float16* W4_16 = W1t16 + (long)ND * NH1;
    _Float16* Br    = W4_16 + (long)ND * NH1;           // 8388608 each
    _Float16* Bl    = Br    + (long)NB * NH2 * NH1;
    _Float16* Lf    = Bl    + (long)NB * NH2 * NH1;     // 16777216 each
    _Float16* Rf    = Lf    + (long)NB * ND * NH2;

    // fc1 + one-time shared prep (1024 fc blocks + 2048 prep blocks)
    fc1_prep<<<NB * NH1 * 4 / 256 + ND * NH1 / 256, 256, 0, stream>>>(
        x, W1, b1, c1, s1, W4, W3, W1t16, W4_16, W3t);

    // fc2, fc3: split-K x8 (low-parallelism links of the serial chain)
    fc_kernel<NH1, NH2, true, 8><<<NB * NH2 * 8 / 256, 256, 0, stream>>>(c1,     W2, b2, out_c2, s2);
    fc_kernel<NH2, NH1, true, 8><<<NB * NH1 * 8 / 256, 256, 0, stream>>>(out_c2, W3, b3, c3,     s3);

    // fc4 + per-batch B prep (2048 fc blocks + 8192 prep blocks)
    fc4_prep<<<NB * ND * 4 / 256 + (long)NB * NH2 * NH1 / 1024, 256, 0, stream>>>(
        c3, W4, b4, out_rec, W2, W3t, s1, s3, Br, Bl);

    // Fused R^T / L GEMMs: M=1024, N=128, K=512 per (batch, side), f16 32x32
    mfma_nk2<<<2048, 256, 0, stream>>>(
        W1t16, W4_16, Br, Bl, s2, Rf, Lf);

    // Jac[b] = L[b] @ R[b] : M=N=1024, K=128, f16 single-pass, XCD-affine
    jac_mfma<<<8192, 256, 0, stream>>>(Lf, Rf, out_jac);
}